// Round 1
// baseline (264.150 us; speedup 1.0000x reference)
//
#include <hip/hip_runtime.h>
#include <cstdint>

// Sudoku iterative-solver, one wave (64 lanes) per board.
// Structure exploited:
//  - f rows (reshaped constraint features) take only 21 distinct values:
//      u in [0,9):   type0, f = [Row[u],Row[u],Row[u]]
//      u in [9,12):  type1, m=u-9, f = [Col[3m],Col[3m+1],Col[3m+2]]
//      u in [12,21): type2, X=u-12, f = [Box[X],Box[X],Box[X]]
//  - cell i uses distinct row dist(i); filling cell q changes exactly rows
//      {q/9, 9+(q%9)/3, 12+box(q)} -> recompute only those 3 per step.
//  - group counts are exact integers; unchanged-row reuse is bit-exact.

__device__ __forceinline__ void wave_fence() {
  asm volatile("s_waitcnt lgkmcnt(0)" ::: "memory");
}

__device__ __forceinline__ int dist_row(int i) {
  int r = i / 27;
  int t = i - 27 * r;
  if (r == 0) return t / 3;
  if (r == 1) return 9 + (t % 3);
  return 12 + 3 * (t / 9) + (t % 3);
}

__device__ __forceinline__ unsigned long long shflx64(unsigned long long v, int m) {
  unsigned lo = (unsigned)v, hi = (unsigned)(v >> 32);
  lo = __shfl_xor(lo, m);
  hi = __shfl_xor(hi, m);
  return ((unsigned long long)hi << 32) | lo;
}

__global__ __launch_bounds__(64, 2)
void sudoku_solver(const float* __restrict__ x, const float* __restrict__ W1g,
                   const float* __restrict__ W2g, float* __restrict__ out) {
  __shared__ float W2s[9][132];      // padded to break bank aliasing
  __shared__ float cnt[3][9][12];    // row/col/box digit counts (fp32 ints)
  __shared__ float hbuf[3][132];     // h for the (up to) 3 recomputed rows
  __shared__ float sful[21][12];     // cached softmax rows (exact fp32)
  __shared__ float rscore[21];       // cached max softmax per row
  __shared__ int   rargs[21];        // cached argmax digit per row
  __shared__ unsigned long long emask[2];  // empty-cell bitmask (81 bits)
  __shared__ float yscr[32];
  __shared__ float escr[32];
  __shared__ int   digc[81];

  const int lane = threadIdx.x;      // 0..63
  const int b = blockIdx.x;          // board id, grid = 2048
  const float* xb = x + b * 729;
  float* ob = out + b * 729;

  // ---- stage W2 into LDS ----
  for (int idx = lane; idx < 1152; idx += 64)
    W2s[idx >> 7][idx & 127] = W2g[idx];

  // ---- W1 rows into registers: lane owns j=lane and j=lane+64 ----
  float w1a[27], w1b[27];
  #pragma unroll
  for (int c = 0; c < 27; ++c) {
    w1a[c] = W1g[lane * 27 + c];
    w1b[c] = W1g[(lane + 64) * 27 + c];
  }

  // ---- zero counts ----
  for (int idx = lane; idx < 3 * 9 * 12; idx += 64)
    ((float*)cnt)[idx] = 0.f;

  // ---- read board, copy x -> out (x_pred init), extract digits ----
  int digA = 0, digB = 0;
  {
    float v[9]; int dg = -1;
    #pragma unroll
    for (int e = 0; e < 9; ++e) v[e] = xb[lane * 9 + e];
    #pragma unroll
    for (int e = 0; e < 9; ++e) { if (v[e] > 0.5f) dg = e; ob[lane * 9 + e] = v[e]; }
    digA = dg; digc[lane] = dg;
    if (lane < 17) {
      const int i2 = 64 + lane;
      float w[9]; int dg2 = -1;
      #pragma unroll
      for (int e = 0; e < 9; ++e) w[e] = xb[i2 * 9 + e];
      #pragma unroll
      for (int e = 0; e < 9; ++e) { if (w[e] > 0.5f) dg2 = e; ob[i2 * 9 + e] = w[e]; }
      digB = dg2; digc[i2] = dg2;
    }
  }
  {
    unsigned long long m0 = __ballot(digA < 0);
    unsigned long long m1 = __ballot((lane < 17) && (digB < 0)) & 0x1FFFFull;
    if (lane == 0) { emask[0] = m0; emask[1] = m1; }
  }
  wave_fence();

  // ---- initial group counts (27 lanes: one (group,index) each) ----
  if (lane < 27) {
    const int g = lane / 9, gi = lane - 9 * g;
    float c9[9];
    #pragma unroll
    for (int e = 0; e < 9; ++e) c9[e] = 0.f;
    #pragma unroll
    for (int k = 0; k < 9; ++k) {
      int cell;
      if (g == 0)      cell = gi * 9 + k;
      else if (g == 1) cell = k * 9 + gi;
      else             cell = (gi / 3) * 27 + (gi % 3) * 3 + (k / 3) * 9 + (k % 3);
      const int dg = digc[cell];
      #pragma unroll
      for (int e = 0; e < 9; ++e) c9[e] += (dg == e) ? 1.f : 0.f;
    }
    #pragma unroll
    for (int e = 0; e < 9; ++e) cnt[g][gi][e] = c9[e];
  }
  wave_fence();

  // ---- recompute 3 distinct rows (fresh, reference arithmetic order) ----
  auto update_rows = [&](int u0, int u1, int u2) {
    // Phase C: h[j] = relu(sum_{c=0..26} f[c]*W1[j][c]), sequential fma chain.
    #pragma unroll
    for (int rr = 0; rr < 3; ++rr) {
      const int u = (rr == 0) ? u0 : (rr == 1) ? u1 : u2;
      int g, gia, gib, gic;
      if (u < 9)       { g = 0; gia = gib = gic = u; }
      else if (u < 12) { g = 1; gia = 3 * (u - 9); gib = gia + 1; gic = gia + 2; }
      else             { g = 2; gia = gib = gic = u - 12; }
      const float* f0 = &cnt[g][gia][0];
      const float* f1 = &cnt[g][gib][0];
      const float* f2 = &cnt[g][gic][0];
      float acc0 = 0.f, acc1 = 0.f;
#define DOT9(FP, BASE)                                                          \
      {                                                                         \
        float4 fA = *(const float4*)(FP);                                       \
        float4 fB = *(const float4*)((FP) + 4);                                 \
        float f8 = (FP)[8];                                                     \
        acc0 = fmaf(fA.x, w1a[BASE+0], acc0); acc1 = fmaf(fA.x, w1b[BASE+0], acc1); \
        acc0 = fmaf(fA.y, w1a[BASE+1], acc0); acc1 = fmaf(fA.y, w1b[BASE+1], acc1); \
        acc0 = fmaf(fA.z, w1a[BASE+2], acc0); acc1 = fmaf(fA.z, w1b[BASE+2], acc1); \
        acc0 = fmaf(fA.w, w1a[BASE+3], acc0); acc1 = fmaf(fA.w, w1b[BASE+3], acc1); \
        acc0 = fmaf(fB.x, w1a[BASE+4], acc0); acc1 = fmaf(fB.x, w1b[BASE+4], acc1); \
        acc0 = fmaf(fB.y, w1a[BASE+5], acc0); acc1 = fmaf(fB.y, w1b[BASE+5], acc1); \
        acc0 = fmaf(fB.z, w1a[BASE+6], acc0); acc1 = fmaf(fB.z, w1b[BASE+6], acc1); \
        acc0 = fmaf(fB.w, w1a[BASE+7], acc0); acc1 = fmaf(fB.w, w1b[BASE+7], acc1); \
        acc0 = fmaf(f8,  w1a[BASE+8], acc0);  acc1 = fmaf(f8,  w1b[BASE+8], acc1);  \
      }
      DOT9(f0, 0)
      DOT9(f1, 9)
      DOT9(f2, 18)
#undef DOT9
      hbuf[rr][lane]      = fmaxf(acc0, 0.f);
      hbuf[rr][64 + lane] = fmaxf(acc1, 0.f);
    }
    wave_fence();

    // Phase D: y[rr][d] = sum_{j=0..127} h[j]*W2[d][j], sequential fma chain.
    const int rrl = lane / 9, dl = lane - 9 * (lane / 9);
    if (lane < 27) {
      const float4* hp = (const float4*)&hbuf[rrl][0];
      const float4* wp = (const float4*)&W2s[dl][0];
      float acc = 0.f;
      #pragma unroll 8
      for (int k = 0; k < 32; ++k) {
        float4 hh = hp[k], ww = wp[k];
        acc = fmaf(hh.x, ww.x, acc);
        acc = fmaf(hh.y, ww.y, acc);
        acc = fmaf(hh.z, ww.z, acc);
        acc = fmaf(hh.w, ww.w, acc);
      }
      yscr[lane] = acc;
    }
    wave_fence();

    // softmax: subtract max, exp, ascending-d sum, literal division.
    float eval = 0.f;
    if (lane < 27) {
      float ymax = yscr[rrl * 9];
      #pragma unroll
      for (int dd = 1; dd < 9; ++dd) ymax = fmaxf(ymax, yscr[rrl * 9 + dd]);
      eval = expf(yscr[lane] - ymax);
      escr[lane] = eval;
    }
    wave_fence();
    if (lane < 27) {
      float S = escr[rrl * 9];
      #pragma unroll
      for (int dd = 1; dd < 9; ++dd) S += escr[rrl * 9 + dd];
      const float s = eval / S;
      const int u = (rrl == 0) ? u0 : (rrl == 1) ? u1 : u2;
      sful[u][dl] = s;
    }
    wave_fence();
    if (lane < 3) {
      const int u = (lane == 0) ? u0 : (lane == 1) ? u1 : u2;
      float best = sful[u][0]; int ba = 0;
      #pragma unroll
      for (int dd = 1; dd < 9; ++dd) {
        float s = sful[u][dd];
        if (s > best) { best = s; ba = dd; }   // strict > keeps first max
      }
      rscore[u] = best; rargs[u] = ba;
    }
    wave_fence();
  };

  // ---- initial 21 rows ----
  #pragma unroll 1
  for (int p = 0; p < 7; ++p) update_rows(3 * p, 3 * p + 1, 3 * p + 2);

  // ---- 81 solver steps ----
  #pragma unroll 1
  for (int step = 0; step < 81; ++step) {
    const unsigned long long mm0 = emask[0], mm1 = emask[1];

    // Phase A: per-cell keys; max-key = (max score, then smallest cell index).
    float s1 = ((mm0 >> lane) & 1ull) ? rscore[dist_row(lane)] : 0.f;
    unsigned long long key =
        ((unsigned long long)__float_as_uint(s1) << 32) | (unsigned)(96 - lane);
    if (lane < 17) {
      const int i2 = 64 + lane;
      float s2 = ((mm1 >> lane) & 1ull) ? rscore[dist_row(i2)] : 0.f;
      unsigned long long k2 =
          ((unsigned long long)__float_as_uint(s2) << 32) | (unsigned)(96 - i2);
      if (k2 > key) key = k2;
    }
    #pragma unroll
    for (int off = 32; off > 0; off >>= 1) {
      unsigned long long o = shflx64(key, off);
      if (o > key) key = o;
    }
    if ((unsigned)(key >> 32) == 0u) continue;  // board complete: no-op step

    const int mmax = 96 - (int)(key & 0xFFFFFFFFull);
    const int du = dist_row(mmax);
    const int digit = rargs[du];
    const int r = mmax / 9, c = mmax - 9 * r;
    const int bx = 3 * (mmax / 27) + c / 3;

    // Phase B: x_pred write for the filled cell; update counts + empty mask.
    if (lane < 3) {
      const int gi = (lane == 0) ? r : (lane == 1) ? c : bx;
      cnt[lane][gi][digit] += 1.f;
    } else if (lane == 3) {
      if (mmax < 64) emask[0] = mm0 & ~(1ull << mmax);
      else           emask[1] = mm1 & ~(1ull << (mmax - 64));
    } else if (lane >= 8 && lane < 17) {
      ob[mmax * 9 + (lane - 8)] = sful[du][lane - 8];
    }
    wave_fence();

    // Phases C/D: recompute the 3 rows affected by this fill.
    update_rows(r, 9 + c / 3, 12 + bx);
  }
}

extern "C" void kernel_launch(void* const* d_in, const int* in_sizes, int n_in,
                              void* d_out, int out_size, void* d_ws, size_t ws_size,
                              hipStream_t stream) {
  const float* x  = (const float*)d_in[0];   // [2048][81][9]
  const float* W1 = (const float*)d_in[1];   // [128][27]
  const float* W2 = (const float*)d_in[2];   // [9][128]
  // d_in[3] = constraint_mask: semantics hardcoded, unused.
  float* out = (float*)d_out;                // [2048][81][9]
  sudoku_solver<<<dim3(2048), dim3(64), 0, stream>>>(x, W1, W2, out);
}

// Round 2
// 242.304 us; speedup vs baseline: 1.0902x; 1.0902x over previous
//
#include <hip/hip_runtime.h>
#include <cstdint>

// Sudoku iterative-solver, one wave (64 lanes) per board.
// Validated in R1: 21 distinct f-rows, dist_row mapping, 3-row update set.
// R2: DPP/swizzle reductions replace LDS round-trips; fused Phase D+softmax;
//     register empty-flags; 4-acc dot; uniform break when solved.

__device__ __forceinline__ void wave_fence() {
  asm volatile("s_waitcnt lgkmcnt(0)" ::: "memory");
}

template <int CTRL>
__device__ __forceinline__ float dppf(float v) {
  return __int_as_float(__builtin_amdgcn_update_dpp(
      0, __float_as_int(v), CTRL, 0xF, 0xF, true));
}
template <int IMM>
__device__ __forceinline__ float swzf(float v) {
  return __int_as_float(__builtin_amdgcn_ds_swizzle(__float_as_int(v), IMM));
}
// xor1 = quad_perm[1,0,3,2]=0xB1, xor2 = quad_perm[2,3,0,1]=0x4E,
// xor8 = row_ror:8 = 0x128 (rotate by half == xor within 16),
// xor4 = ds_swizzle 0x101F, xor16 = ds_swizzle 0x401F.
__device__ __forceinline__ float redmax16(float v) {
  v = fmaxf(v, dppf<0xB1>(v));
  v = fmaxf(v, dppf<0x4E>(v));
  v = fmaxf(v, swzf<0x101F>(v));
  v = fmaxf(v, dppf<0x128>(v));
  return v;
}
__device__ __forceinline__ float redsum16(float v) {
  v += dppf<0xB1>(v);
  v += dppf<0x4E>(v);
  v += swzf<0x101F>(v);
  v += dppf<0x128>(v);
  return v;
}
__device__ __forceinline__ float redmax64(float v) {
  v = fmaxf(v, dppf<0xB1>(v));
  v = fmaxf(v, dppf<0x4E>(v));
  v = fmaxf(v, swzf<0x101F>(v));
  v = fmaxf(v, dppf<0x128>(v));
  v = fmaxf(v, swzf<0x401F>(v));
  v = fmaxf(v, __shfl_xor(v, 32));
  return v;
}

__device__ __forceinline__ int dist_row(int i) {
  int r = i / 27;
  int t = i - 27 * r;
  if (r == 0) return t / 3;
  if (r == 1) return 9 + (t % 3);
  return 12 + 3 * (t / 9) + (t % 3);
}

__global__ __launch_bounds__(64, 2)
void sudoku_solver(const float* __restrict__ x, const float* __restrict__ W1g,
                   const float* __restrict__ W2g, float* __restrict__ out) {
  __shared__ float W2s[9][132];      // padded: 132 breaks bank aliasing
  __shared__ float cnt[3][9][12];    // row/col/box digit counts (fp32 ints)
  __shared__ float hbuf[3][132];     // h for the 3 recomputed rows (padded)
  __shared__ float sful[21][12];     // cached softmax rows
  __shared__ float rscore[21];       // cached max softmax per row
  __shared__ int   rargs[21];        // cached argmax digit per row
  __shared__ int   digc[81];

  const int lane = threadIdx.x;      // 0..63
  const int b = blockIdx.x;
  const float* xb = x + b * 729;
  float* ob = out + b * 729;

  // ---- stage W2 into LDS ----
  for (int idx = lane; idx < 1152; idx += 64)
    W2s[idx >> 7][idx & 127] = W2g[idx];

  // ---- W1 rows into registers: lane owns j=lane and j=lane+64 ----
  float w1a[27], w1b[27];
  #pragma unroll
  for (int c = 0; c < 27; ++c) {
    w1a[c] = W1g[lane * 27 + c];
    w1b[c] = W1g[(lane + 64) * 27 + c];
  }

  for (int idx = lane; idx < 3 * 9 * 12; idx += 64)
    ((float*)cnt)[idx] = 0.f;

  // ---- read board, ob = x, extract digits, empty flags in registers ----
  bool eA, eB = false;
  {
    float v[9]; int dg = -1;
    #pragma unroll
    for (int e = 0; e < 9; ++e) v[e] = xb[lane * 9 + e];
    #pragma unroll
    for (int e = 0; e < 9; ++e) { if (v[e] > 0.5f) dg = e; ob[lane * 9 + e] = v[e]; }
    eA = (dg < 0); digc[lane] = dg;
    if (lane < 17) {
      const int i2 = 64 + lane;
      float w[9]; int dg2 = -1;
      #pragma unroll
      for (int e = 0; e < 9; ++e) w[e] = xb[i2 * 9 + e];
      #pragma unroll
      for (int e = 0; e < 9; ++e) { if (w[e] > 0.5f) dg2 = e; ob[i2 * 9 + e] = w[e]; }
      eB = (dg2 < 0); digc[i2] = dg2;
    }
  }
  const int distA = dist_row(lane);
  const int distB = (lane < 17) ? dist_row(64 + lane) : 0;
  wave_fence();

  // ---- initial group counts (27 lanes) ----
  if (lane < 27) {
    const int g = lane / 9, gi = lane - 9 * g;
    float c9[9];
    #pragma unroll
    for (int e = 0; e < 9; ++e) c9[e] = 0.f;
    #pragma unroll
    for (int k = 0; k < 9; ++k) {
      int cell;
      if (g == 0)      cell = gi * 9 + k;
      else if (g == 1) cell = k * 9 + gi;
      else             cell = (gi / 3) * 27 + (gi % 3) * 3 + (k / 3) * 9 + (k % 3);
      const int dg = digc[cell];
      #pragma unroll
      for (int e = 0; e < 9; ++e) c9[e] += (dg == e) ? 1.f : 0.f;
    }
    #pragma unroll
    for (int e = 0; e < 9; ++e) cnt[g][gi][e] = c9[e];
  }
  wave_fence();

  // Phase D lane roles (fixed): L = 16*rr + dl
  const int rr3 = lane >> 4;         // 0..3 (3 invalid)
  const int dl  = lane & 15;         // 0..15 (>8 invalid)
  const bool dval = (rr3 < 3) && (dl < 9);
  const float* hrow = hbuf[(rr3 < 3) ? rr3 : 0];
  const float* wrow = W2s[(dl < 9) ? dl : 0];

  // ---- recompute 3 rows: MLP + softmax + row argmax, fused ----
  auto update_rows = [&](int u0, int u1, int u2) {
    // Phase C: h[j] = relu(sum_c f[c]*W1[j][c]) for the 3 rows, all 64 lanes.
    #pragma unroll
    for (int rr = 0; rr < 3; ++rr) {
      const int u = (rr == 0) ? u0 : (rr == 1) ? u1 : u2;
      int g, gia, gib, gic;
      if (u < 9)       { g = 0; gia = gib = gic = u; }
      else if (u < 12) { g = 1; gia = 3 * (u - 9); gib = gia + 1; gic = gia + 2; }
      else             { g = 2; gia = gib = gic = u - 12; }
      const float* f0 = &cnt[g][gia][0];
      const float* f1 = &cnt[g][gib][0];
      const float* f2 = &cnt[g][gic][0];
      float acc0 = 0.f, acc1 = 0.f;
#define DOT9(FP, BASE)                                                          \
      {                                                                         \
        float4 fA = *(const float4*)(FP);                                       \
        float4 fB = *(const float4*)((FP) + 4);                                 \
        float f8 = (FP)[8];                                                     \
        acc0 = fmaf(fA.x, w1a[BASE+0], acc0); acc1 = fmaf(fA.x, w1b[BASE+0], acc1); \
        acc0 = fmaf(fA.y, w1a[BASE+1], acc0); acc1 = fmaf(fA.y, w1b[BASE+1], acc1); \
        acc0 = fmaf(fA.z, w1a[BASE+2], acc0); acc1 = fmaf(fA.z, w1b[BASE+2], acc1); \
        acc0 = fmaf(fA.w, w1a[BASE+3], acc0); acc1 = fmaf(fA.w, w1b[BASE+3], acc1); \
        acc0 = fmaf(fB.x, w1a[BASE+4], acc0); acc1 = fmaf(fB.x, w1b[BASE+4], acc1); \
        acc0 = fmaf(fB.y, w1a[BASE+5], acc0); acc1 = fmaf(fB.y, w1b[BASE+5], acc1); \
        acc0 = fmaf(fB.z, w1a[BASE+6], acc0); acc1 = fmaf(fB.z, w1b[BASE+6], acc1); \
        acc0 = fmaf(fB.w, w1a[BASE+7], acc0); acc1 = fmaf(fB.w, w1b[BASE+7], acc1); \
        acc0 = fmaf(f8,  w1a[BASE+8], acc0);  acc1 = fmaf(f8,  w1b[BASE+8], acc1);  \
      }
      DOT9(f0, 0)
      DOT9(f1, 9)
      DOT9(f2, 18)
#undef DOT9
      hbuf[rr][lane]      = fmaxf(acc0, 0.f);
      hbuf[rr][64 + lane] = fmaxf(acc1, 0.f);
    }
    wave_fence();

    // Phase D: y = h . W2[d] with 4 accumulators; then in-register softmax
    // + row argmax via 16-wide DPP/swizzle butterflies. One fence total.
    float a0 = 0.f, a1 = 0.f, a2 = 0.f, a3 = 0.f;
    const float4* hp = (const float4*)hrow;
    const float4* wp = (const float4*)wrow;
    #pragma unroll
    for (int k = 0; k < 32; k += 4) {
      float4 h0 = hp[k],     ww0 = wp[k];
      float4 h1 = hp[k + 1], ww1 = wp[k + 1];
      float4 h2 = hp[k + 2], ww2 = wp[k + 2];
      float4 h3 = hp[k + 3], ww3 = wp[k + 3];
      a0 = fmaf(h0.x, ww0.x, a0); a0 = fmaf(h0.y, ww0.y, a0);
      a0 = fmaf(h0.z, ww0.z, a0); a0 = fmaf(h0.w, ww0.w, a0);
      a1 = fmaf(h1.x, ww1.x, a1); a1 = fmaf(h1.y, ww1.y, a1);
      a1 = fmaf(h1.z, ww1.z, a1); a1 = fmaf(h1.w, ww1.w, a1);
      a2 = fmaf(h2.x, ww2.x, a2); a2 = fmaf(h2.y, ww2.y, a2);
      a2 = fmaf(h2.z, ww2.z, a2); a2 = fmaf(h2.w, ww2.w, a2);
      a3 = fmaf(h3.x, ww3.x, a3); a3 = fmaf(h3.y, ww3.y, a3);
      a3 = fmaf(h3.z, ww3.z, a3); a3 = fmaf(h3.w, ww3.w, a3);
    }
    float y = (a0 + a1) + (a2 + a3);
    y = dval ? y : -1e30f;
    const float ymax = redmax16(y);
    const float ev = dval ? expf(y - ymax) : 0.f;
    const float S = redsum16(ev);
    const float s = ev / S;                       // garbage on invalid lanes
    const float sm = dval ? s : 0.f;
    const float rmax = redmax16(sm);
    unsigned long long bm = __ballot(dval && (sm == rmax));
    const int u = (rr3 == 0) ? u0 : (rr3 == 1) ? u1 : u2;
    if (dval) sful[u][dl] = s;
    if (rr3 < 3 && dl == 0) {
      rscore[u] = rmax;
      rargs[u] = __builtin_ctz((unsigned)((bm >> (rr3 * 16)) & 0xFFFFull));
    }
    wave_fence();
  };

  // ---- initial 21 rows ----
  #pragma unroll 1
  for (int p = 0; p < 7; ++p) update_rows(3 * p, 3 * p + 1, 3 * p + 2);

  // ---- solver steps ----
  #pragma unroll 1
  for (int step = 0; step < 81; ++step) {
    // Phase A: wave argmax over empty cells (score max + first-index tie).
    const float sA = eA ? rscore[distA] : 0.f;
    const float sB = (lane < 17 && eB) ? rscore[distB] : 0.f;
    const float M = redmax64(fmaxf(sA, sB));
    if (M <= 0.f) break;                      // uniform: board solved

    const unsigned long long m0 = __ballot(sA == M);
    const unsigned long long m1 = __ballot((lane < 17) && (sB == M));
    const int mmax = m0 ? __builtin_ctzll(m0) : 64 + __builtin_ctzll(m1);

    const int du = dist_row(mmax);
    const int r = mmax / 9, c = mmax - 9 * r;
    const int bx = (mmax / 27) * 3 + c / 3;
    const int digit = rargs[du];

    // Phase B: counts += fill; x_pred write for the filled cell.
    if (lane < 3) {
      const int gi = (lane == 0) ? r : (lane == 1) ? c : bx;
      cnt[lane][gi][digit] += 1.f;
    } else if (lane >= 8 && lane < 17) {
      ob[mmax * 9 + (lane - 8)] = sful[du][lane - 8];
    }
    if (lane == mmax) eA = false;
    if (lane + 64 == mmax) eB = false;
    wave_fence();

    update_rows(r, 9 + c / 3, 12 + bx);
  }
}

extern "C" void kernel_launch(void* const* d_in, const int* in_sizes, int n_in,
                              void* d_out, int out_size, void* d_ws, size_t ws_size,
                              hipStream_t stream) {
  const float* x  = (const float*)d_in[0];   // [2048][81][9]
  const float* W1 = (const float*)d_in[1];   // [128][27]
  const float* W2 = (const float*)d_in[2];   // [9][128]
  float* out = (float*)d_out;                // [2048][81][9]
  sudoku_solver<<<dim3(2048), dim3(64), 0, stream>>>(x, W1, W2, out);
}